// Round 9
// baseline (853.942 us; speedup 1.0000x reference)
//
#include <hip/hip_runtime.h>
#include <hip/hip_bf16.h>
#include <cstdint>
#include <cstddef>

#define N_TOK 65536
#define HIDDEN 768
#define NHEAD 12
#define HEADD 64

typedef __bf16 bf16x8 __attribute__((ext_vector_type(8)));
typedef float f32x4 __attribute__((ext_vector_type(4)));

__device__ __forceinline__ float bflo(unsigned int u) {
  return __builtin_bit_cast(float, (unsigned int)(u << 16));
}
__device__ __forceinline__ float bfhi(unsigned int u) {
  return __builtin_bit_cast(float, (unsigned int)(u & 0xffff0000u));
}
__device__ __forceinline__ unsigned short f2bf(float f) {
  unsigned int x = __builtin_bit_cast(unsigned int, f);
  unsigned int r = x + 0x7fffu + ((x >> 16) & 1u);  // RTNE
  return (unsigned short)(r >> 16);
}

__device__ __forceinline__ void gload_lds16(const void* g, void* l) {
  __builtin_amdgcn_global_load_lds(
      (const __attribute__((address_space(1))) void*)g,
      (__attribute__((address_space(3))) void*)l, 16, 0, 0);
}

// Full bank swizzle: physical = logical ^ ((row&7)<<4).  (verified: 0 conflicts)
__device__ __forceinline__ bf16x8 ldsfrag(const char* base, int row, int kb) {
  int L = (row << 7) + kb;        // 128 B rows
  L ^= (row & 7) << 4;
  return *(const bf16x8*)(base + L);
}

// ------- converts: x + 4 weights (no bias concat needed anymore) -------
// blocks [0, 49152): x cvt; [49152, 51456): weight cvt (576 per matrix)
__global__ void cvt_all_kernel(const float* __restrict__ x,
                               const float* __restrict__ Wq, const float* __restrict__ Wk,
                               const float* __restrict__ Wv, const float* __restrict__ Wo,
                               unsigned short* __restrict__ x_bf,
                               unsigned short* __restrict__ wq_bf,
                               unsigned short* __restrict__ wk_bf,
                               unsigned short* __restrict__ wv_bf,
                               unsigned short* __restrict__ wo_bf) {
  const int bid = blockIdx.x;
  if (bid < 49152) {
    const int idx = bid * 256 + threadIdx.x;
    float4 v = ((const float4*)x)[idx];
    ushort4 o;
    o.x = f2bf(v.x); o.y = f2bf(v.y); o.z = f2bf(v.z); o.w = f2bf(v.w);
    ((ushort4*)x_bf)[idx] = o;
  } else {
    const int wb = bid - 49152;
    const int mat = wb / 576;
    const int idx = (wb - mat * 576) * 256 + threadIdx.x;
    const float* src = mat == 0 ? Wq : mat == 1 ? Wk : mat == 2 ? Wv : Wo;
    unsigned short* dst = mat == 0 ? wq_bf : mat == 1 ? wk_bf : mat == 2 ? wv_bf : wo_bf;
    float4 v = ((const float4*)src)[idx];
    ushort4 o;
    o.x = f2bf(v.x); o.y = f2bf(v.y); o.z = f2bf(v.z); o.w = f2bf(v.w);
    ((ushort4*)dst)[idx] = o;
  }
}

// ------------- 256x256 bf16 GEMM, C = A @ B^T + bias (R4/R8 config) -------------
// MODE 0: bf16 out at C[row*ldc+col].
// MODE 1: f32 out.
// MODE 2: bf16 out, K-transpose remap within token row:
//         C[row*ldc + 768 + (col%12)*64 + col/12]   (head-major K for attn)
template <int MODE>
__global__ __launch_bounds__(512, 2)
void gemm256(const unsigned short* __restrict__ A,
             const unsigned short* __restrict__ B,
             const float* __restrict__ bias,
             void* __restrict__ C, int K, int NBLK, int ldc) {
  __shared__ __align__(16) char lds[131072];
  const int tid = threadIdx.x;
  const int lane = tid & 63;
  const int wave = tid >> 6;
  const int wr = wave >> 2;   // 0..1
  const int wc = wave & 3;    // 0..3

  // XCD-aware bijective swizzle (grid % 8 == 0 by construction)
  const int nwg = gridDim.x;
  const int bid = blockIdx.x;
  const int wg = (bid & 7) * (nwg >> 3) + (bid >> 3);
  const int mb = wg / NBLK;
  const int nb = wg - mb * NBLK;
  const int brow = mb << 8;
  const int bcol = nb << 8;

  // staging: linear LDS dest (tid*16), inverse-swizzled global source
  const int Ld = tid * 16;
  const int Ls = Ld ^ (((tid >> 3) & 7) << 4);
  const int sr = Ls >> 7;           // source row within 64-row chunk
  const int sc = (Ls & 127) >> 1;   // source col element

  const int NT = K >> 6;

#define STAGE(Mat, panelRow, bufbase, matoff, half, kt)                         \
  do {                                                                          \
    const unsigned short* _s =                                                  \
        (Mat) + (size_t)((panelRow) + (half) * 128 + sr) * K + ((kt) << 6) + sc;\
    char* _d = (char*)lds + (bufbase) + (matoff) + ((half) << 14) + Ld;         \
    gload_lds16(_s, _d);                                                        \
    gload_lds16(_s + ((size_t)K << 6), _d + 8192);                              \
  } while (0)

  f32x4 acc[8][4];
#pragma unroll
  for (int m = 0; m < 8; ++m)
#pragma unroll
    for (int n = 0; n < 4; ++n) acc[m][n] = (f32x4){0.f, 0.f, 0.f, 0.f};

  const int arow = wr * 128 + (lane & 15);
  const int nrow = wc * 64 + (lane & 15);
  const int kpart = (lane >> 4) * 16;  // byte offset of this lane's k-slice

  // ---- prologue: stage tile 0 (A,B), drain, barrier ----
  STAGE(A, brow, 0, 0, 0, 0);
  STAGE(A, brow, 0, 0, 1, 0);
  STAGE(B, bcol, 0, 32768, 0, 0);
  STAGE(B, bcol, 0, 32768, 1, 0);
  asm volatile("s_waitcnt vmcnt(0)" ::: "memory");
  __builtin_amdgcn_s_barrier();

  for (int t = 0; t < NT; ++t) {
    const int cur = t & 1;
    const char* la = lds + cur * 65536;
    const char* lb = la + 32768;
    const int obuf = (cur ^ 1) * 65536;  // buffer for tile t+1

    bf16x8 aLo[8], aHi[8], bLo[4], bHi[4];

    // -------- PH1: read aLo(8)+bLo(4); stage A(t+1); MFMA Q(lo,lo) --------
#pragma unroll
    for (int m = 0; m < 4; ++m)
#pragma unroll
      for (int kk = 0; kk < 2; ++kk)
        aLo[m * 2 + kk] = ldsfrag(la, arow + m * 16, kk * 64 + kpart);
#pragma unroll
    for (int n = 0; n < 2; ++n)
#pragma unroll
      for (int kk = 0; kk < 2; ++kk)
        bLo[n * 2 + kk] = ldsfrag(lb, nrow + n * 16, kk * 64 + kpart);
    if (t + 1 < NT) {
      STAGE(A, brow, obuf, 0, 0, t + 1);
      STAGE(A, brow, obuf, 0, 1, t + 1);
    }
    __builtin_amdgcn_s_barrier();
    asm volatile("s_waitcnt lgkmcnt(0)" ::: "memory");
    __builtin_amdgcn_s_setprio(1);
#pragma unroll
    for (int m = 0; m < 4; ++m)
#pragma unroll
      for (int n = 0; n < 2; ++n)
#pragma unroll
        for (int kk = 0; kk < 2; ++kk)
          acc[m][n] = __builtin_amdgcn_mfma_f32_16x16x32_bf16(
              aLo[m * 2 + kk], bLo[n * 2 + kk], acc[m][n], 0, 0, 0);
    __builtin_amdgcn_s_setprio(0);

    // -------- PH2: read aHi(8); stage B(t+1); MFMA Q(hi,lo) --------
#pragma unroll
    for (int m = 0; m < 4; ++m)
#pragma unroll
      for (int kk = 0; kk < 2; ++kk)
        aHi[m * 2 + kk] = ldsfrag(la, arow + 64 + m * 16, kk * 64 + kpart);
    if (t + 1 < NT) {
      STAGE(B, bcol, obuf, 32768, 0, t + 1);
      STAGE(B, bcol, obuf, 32768, 1, t + 1);
    }
    __builtin_amdgcn_s_barrier();
    asm volatile("s_waitcnt lgkmcnt(0)" ::: "memory");
    __builtin_amdgcn_s_setprio(1);
#pragma unroll
    for (int m = 0; m < 4; ++m)
#pragma unroll
      for (int n = 0; n < 2; ++n)
#pragma unroll
        for (int kk = 0; kk < 2; ++kk)
          acc[4 + m][n] = __builtin_amdgcn_mfma_f32_16x16x32_bf16(
              aHi[m * 2 + kk], bLo[n * 2 + kk], acc[4 + m][n], 0, 0, 0);
    __builtin_amdgcn_s_setprio(0);

    // -------- PH3: read bHi(4); MFMA Q(hi,hi) --------
#pragma unroll
    for (int n = 0; n < 2; ++n)
#pragma unroll
      for (int kk = 0; kk < 2; ++kk)
        bHi[n * 2 + kk] = ldsfrag(lb, nrow + 32 + n * 16, kk * 64 + kpart);
    __builtin_amdgcn_s_barrier();
    asm volatile("s_waitcnt lgkmcnt(0)" ::: "memory");
    __builtin_amdgcn_s_setprio(1);
#pragma unroll
    for (int m = 0; m < 4; ++m)
#pragma unroll
      for (int n = 0; n < 2; ++n)
#pragma unroll
        for (int kk = 0; kk < 2; ++kk)
          acc[4 + m][n + 2] = __builtin_amdgcn_mfma_f32_16x16x32_bf16(
              aHi[m * 2 + kk], bHi[n * 2 + kk], acc[4 + m][n + 2], 0, 0, 0);
    __builtin_amdgcn_s_setprio(0);

    // -------- PH4: vmcnt drain (t+1 staged >=2 phases ago); MFMA Q(lo,hi) --
    asm volatile("s_waitcnt vmcnt(0)" ::: "memory");
    __builtin_amdgcn_s_barrier();
    __builtin_amdgcn_s_setprio(1);
#pragma unroll
    for (int m = 0; m < 4; ++m)
#pragma unroll
      for (int n = 0; n < 2; ++n)
#pragma unroll
        for (int kk = 0; kk < 2; ++kk)
          acc[m][n + 2] = __builtin_amdgcn_mfma_f32_16x16x32_bf16(
              aLo[m * 2 + kk], bHi[n * 2 + kk], acc[m][n + 2], 0, 0, 0);
    __builtin_amdgcn_s_setprio(0);
  }
#undef STAGE

  // ---------------- epilogue ----------------
  const int crow0 = brow + wr * 128 + (lane >> 4) * 4;
  const int ccol0 = bcol + wc * 64 + (lane & 15);
#pragma unroll
  for (int m = 0; m < 8; ++m) {
#pragma unroll
    for (int n = 0; n < 4; ++n) {
      const int col = ccol0 + n * 16;
      const float bv = bias[col];
#pragma unroll
      for (int r = 0; r < 4; ++r) {
        const int row = crow0 + m * 16 + r;
        const float v = acc[m][n][r] + bv;
        if (MODE == 1) {
          ((float*)C)[(size_t)row * ldc + col] = v;
        } else if (MODE == 2) {
          const int g = col % 12;
          const int d = col / 12;
          ((unsigned short*)C)[(size_t)row * ldc + 768 + g * 64 + d] = f2bf(v);
        } else {
          ((unsigned short*)C)[(size_t)row * ldc + col] = f2bf(v);
        }
      }
    }
  }
}

// ---------------- per-token 12x12 attention (head-major K) -----------------
// qkv row layout: Q[h][d] | KT[g][d] | V[g][d]  (each 12x64 bf16)
__global__ void attn_kernel(const unsigned short* __restrict__ qkv,
                            unsigned short* __restrict__ ctx) {
  const int gtid = blockIdx.x * blockDim.x + threadIdx.x;
  const int t = gtid / 12;
  const int h = gtid - t * 12;
  if (t >= N_TOK) return;

  const unsigned short* row = qkv + (size_t)t * 2304;
  const unsigned short* qp = row + h * 64;
  const unsigned short* kp = row + 768;

  // Q into registers (64 floats)
  float qd[64];
#pragma unroll
  for (int c = 0; c < 8; ++c) {
    const uint4 qc = *(const uint4*)(qp + c * 8);
    const unsigned int qw[4] = {qc.x, qc.y, qc.z, qc.w};
#pragma unroll
    for (int w = 0; w < 4; ++w) {
      qd[c * 8 + 2 * w] = bflo(qw[w]);
      qd[c * 8 + 2 * w + 1] = bfhi(qw[w]);
    }
  }

  float s[12];
#pragma unroll
  for (int g = 0; g < 12; ++g) {
    float a = 0.f;
#pragma unroll
    for (int c = 0; c < 8; ++c) {
      const uint4 kc = *(const uint4*)(kp + g * 64 + c * 8);
      const unsigned int kw[4] = {kc.x, kc.y, kc.z, kc.w};
#pragma unroll
      for (int w = 0; w < 4; ++w) {
        a += qd[c * 8 + 2 * w] * bflo(kw[w]);
        a += qd[c * 8 + 2 * w + 1] * bfhi(kw[w]);
      }
    }
    s[g] = a;
  }

  float mx = s[0];
#pragma unroll
  for (int g = 1; g < 12; ++g) mx = fmaxf(mx, s[g]);
  float p[12];
  float sum = 0.f;
#pragma unroll
  for (int g = 0; g < 12; ++g) {
    p[g] = __expf((s[g] - mx) * 0.125f);
    sum += p[g];
  }
  const float inv = 1.0f / sum;
#pragma unroll
  for (int g = 0; g < 12; ++g) p[g] *= inv;

  const unsigned short* vp = row + 1536;
  unsigned short* op = ctx + (size_t)t * 768 + h * 64;
  for (int c = 0; c < 8; ++c) {
    float o[8];
#pragma unroll
    for (int k = 0; k < 8; ++k) o[k] = 0.f;
#pragma unroll
    for (int g = 0; g < 12; ++g) {
      const uint4 vv = *(const uint4*)(vp + g * 64 + c * 8);
      const unsigned int vw[4] = {vv.x, vv.y, vv.z, vv.w};
#pragma unroll
      for (int k = 0; k < 4; ++k) {
        o[2 * k] += p[g] * bflo(vw[k]);
        o[2 * k + 1] += p[g] * bfhi(vw[k]);
      }
    }
    uint4 w;
    w.x = (unsigned int)f2bf(o[0]) | ((unsigned int)f2bf(o[1]) << 16);
    w.y = (unsigned int)f2bf(o[2]) | ((unsigned int)f2bf(o[3]) << 16);
    w.z = (unsigned int)f2bf(o[4]) | ((unsigned int)f2bf(o[5]) << 16);
    w.w = (unsigned int)f2bf(o[6]) | ((unsigned int)f2bf(o[7]) << 16);
    *(uint4*)(op + c * 8) = w;
  }
}

extern "C" void kernel_launch(void* const* d_in, const int* in_sizes, int n_in,
                              void* d_out, int out_size, void* d_ws, size_t ws_size,
                              hipStream_t stream) {
  const float* x = (const float*)d_in[0];
  const float* Wq = (const float*)d_in[1];
  const float* bq = (const float*)d_in[2];
  const float* Wk = (const float*)d_in[3];
  const float* bk = (const float*)d_in[4];
  const float* Wv = (const float*)d_in[5];
  const float* bv = (const float*)d_in[6];
  const float* Wo = (const float*)d_in[7];
  const float* bo = (const float*)d_in[8];
  float* out = (float*)d_out;

  char* ws = (char*)d_ws;
  unsigned short* x_bf = (unsigned short*)ws;
  unsigned short* ctx = (unsigned short*)ws;  // alias: x_bf dead before attn
  unsigned short* qkv = (unsigned short*)(ws + 100663296u);
  unsigned short* wq_bf = (unsigned short*)(ws + 402653184u);
  unsigned short* wk_bf = (unsigned short*)(ws + 403832832u);
  unsigned short* wv_bf = (unsigned short*)(ws + 405012480u);
  unsigned short* wo_bf = (unsigned short*)(ws + 406192128u);

  // converts (x + 4 weights) in one launch
  cvt_all_kernel<<<51456, 256, 0, stream>>>(x, Wq, Wk, Wv, Wo,
                                            x_bf, wq_bf, wk_bf, wv_bf, wo_bf);

  // Q / K / V GEMMs: [65536 x 768] @ [768 x 768]^T + b -> qkv sections
  const int g3 = (N_TOK / 256) * 3;  // 768 blocks each
  gemm256<0><<<g3, 512, 0, stream>>>(x_bf, wq_bf, bq, qkv, HIDDEN, 3, 2304);
  gemm256<2><<<g3, 512, 0, stream>>>(x_bf, wk_bf, bk, qkv, HIDDEN, 3, 2304);
  gemm256<0><<<g3, 512, 0, stream>>>(x_bf, wv_bf, bv, qkv + 1536, HIDDEN, 3, 2304);

  // per-token attention -> ctx bf16
  attn_kernel<<<(N_TOK * NHEAD) / 256, 256, 0, stream>>>(qkv, ctx);

  // output projection: [65536 x 768] @ [768 x 768]^T + bo -> out f32
  gemm256<1><<<(N_TOK / 256) * (HIDDEN / 256), 512, 0, stream>>>(
      ctx, wo_bf, bo, out, HIDDEN, HIDDEN / 256, HIDDEN);
}

// Round 10
// 619.443 us; speedup vs baseline: 1.3786x; 1.3786x over previous
//
#include <hip/hip_runtime.h>
#include <hip/hip_bf16.h>
#include <cstdint>
#include <cstddef>

#define N_TOK 65536
#define HIDDEN 768
#define NHEAD 12
#define HEADD 64

typedef __bf16 bf16x8 __attribute__((ext_vector_type(8)));
typedef float f32x4 __attribute__((ext_vector_type(4)));

__device__ __forceinline__ float bflo(unsigned int u) {
  return __builtin_bit_cast(float, (unsigned int)(u << 16));
}
__device__ __forceinline__ float bfhi(unsigned int u) {
  return __builtin_bit_cast(float, (unsigned int)(u & 0xffff0000u));
}
__device__ __forceinline__ unsigned short f2bf(float f) {
  unsigned int x = __builtin_bit_cast(unsigned int, f);
  unsigned int r = x + 0x7fffu + ((x >> 16) & 1u);  // RTNE
  return (unsigned short)(r >> 16);
}

__device__ __forceinline__ void gload_lds16(const void* g, void* l) {
  __builtin_amdgcn_global_load_lds(
      (const __attribute__((address_space(1))) void*)g,
      (__attribute__((address_space(3))) void*)l, 16, 0, 0);
}

// Full bank swizzle: physical = logical ^ ((row&7)<<4).  (verified: 0 conflicts)
__device__ __forceinline__ bf16x8 ldsfrag(const char* base, int row, int kb) {
  int L = (row << 7) + kb;        // 128 B rows
  L ^= (row & 7) << 4;
  return *(const bf16x8*)(base + L);
}

// generic within-row swizzle for attn LDS (breaks 128B-stride bank collisions)
__device__ __forceinline__ int swz(int loff) {
  return loff ^ (((loff >> 7) & 7) << 4);
}

// ------- ALL converts in one launch: x, 4 weights, bias concat -------
__global__ void cvt_all_kernel(const float* __restrict__ x,
                               const float* __restrict__ Wq, const float* __restrict__ Wk,
                               const float* __restrict__ Wv, const float* __restrict__ Wo,
                               const float* __restrict__ bq, const float* __restrict__ bk,
                               const float* __restrict__ bv,
                               unsigned short* __restrict__ x_bf,
                               unsigned short* __restrict__ wqkv,
                               unsigned short* __restrict__ wo_bf,
                               float* __restrict__ bqkv) {
  const int bid = blockIdx.x;
  if (bid < 49152) {
    const int idx = bid * 256 + threadIdx.x;
    float4 v = ((const float4*)x)[idx];
    ushort4 o;
    o.x = f2bf(v.x); o.y = f2bf(v.y); o.z = f2bf(v.z); o.w = f2bf(v.w);
    ((ushort4*)x_bf)[idx] = o;
  } else if (bid < 51456) {
    const int wb = bid - 49152;
    const int mat = wb / 576;
    const int idx = (wb - mat * 576) * 256 + threadIdx.x;
    const float* src = mat == 0 ? Wq : mat == 1 ? Wk : mat == 2 ? Wv : Wo;
    unsigned short* dst = (mat == 3) ? wo_bf : wqkv + mat * (HIDDEN * HIDDEN);
    float4 v = ((const float4*)src)[idx];
    ushort4 o;
    o.x = f2bf(v.x); o.y = f2bf(v.y); o.z = f2bf(v.z); o.w = f2bf(v.w);
    ((ushort4*)dst)[idx] = o;
  } else {
    const int i = (bid - 51456) * 256 + threadIdx.x;
    if (i < 576) {
      const float* src = i < 192 ? bq : i < 384 ? bk : bv;
      const int off = i < 192 ? i : i < 384 ? i - 192 : i - 384;
      ((float4*)bqkv)[i] = ((const float4*)src)[off];
    }
  }
}

// ------------- 256x256 bf16 GEMM, C = A @ B^T + bias -------------
// MODE 0: bf16 out.  MODE 1: f32 out.
// MODE 3: bf16 out, fused QKV: cols [768,1536) (K section) stored head-major:
//         kc=col-768 -> 768 + (kc%12)*64 + kc/12   (numerics verified R9)
template <int MODE>
__global__ __launch_bounds__(512, 2)
void gemm256(const unsigned short* __restrict__ A,
             const unsigned short* __restrict__ B,
             const float* __restrict__ bias,
             void* __restrict__ C, int K, int NBLK, int ldc) {
  __shared__ __align__(16) char lds[131072];
  const int tid = threadIdx.x;
  const int lane = tid & 63;
  const int wave = tid >> 6;
  const int wr = wave >> 2;   // 0..1
  const int wc = wave & 3;    // 0..3

  const int nwg = gridDim.x;
  const int bid = blockIdx.x;
  const int wg = (bid & 7) * (nwg >> 3) + (bid >> 3);
  const int mb = wg / NBLK;
  const int nb = wg - mb * NBLK;
  const int brow = mb << 8;
  const int bcol = nb << 8;

  const int Ld = tid * 16;
  const int Ls = Ld ^ (((tid >> 3) & 7) << 4);
  const int sr = Ls >> 7;
  const int sc = (Ls & 127) >> 1;

  const int NT = K >> 6;

#define STAGE(Mat, panelRow, bufbase, matoff, half, kt)                         \
  do {                                                                          \
    const unsigned short* _s =                                                  \
        (Mat) + (size_t)((panelRow) + (half) * 128 + sr) * K + ((kt) << 6) + sc;\
    char* _d = (char*)lds + (bufbase) + (matoff) + ((half) << 14) + Ld;         \
    gload_lds16(_s, _d);                                                        \
    gload_lds16(_s + ((size_t)K << 6), _d + 8192);                              \
  } while (0)

  f32x4 acc[8][4];
#pragma unroll
  for (int m = 0; m < 8; ++m)
#pragma unroll
    for (int n = 0; n < 4; ++n) acc[m][n] = (f32x4){0.f, 0.f, 0.f, 0.f};

  const int arow = wr * 128 + (lane & 15);
  const int nrow = wc * 64 + (lane & 15);
  const int kpart = (lane >> 4) * 16;

  STAGE(A, brow, 0, 0, 0, 0);
  STAGE(A, brow, 0, 0, 1, 0);
  STAGE(B, bcol, 0, 32768, 0, 0);
  STAGE(B, bcol, 0, 32768, 1, 0);
  asm volatile("s_waitcnt vmcnt(0)" ::: "memory");
  __builtin_amdgcn_s_barrier();

  for (int t = 0; t < NT; ++t) {
    const int cur = t & 1;
    const char* la = lds + cur * 65536;
    const char* lb = la + 32768;
    const int obuf = (cur ^ 1) * 65536;

    bf16x8 aLo[8], aHi[8], bLo[4], bHi[4];

    // PH1: read aLo+bLo; stage A(t+1); MFMA Q(lo,lo)
#pragma unroll
    for (int m = 0; m < 4; ++m)
#pragma unroll
      for (int kk = 0; kk < 2; ++kk)
        aLo[m * 2 + kk] = ldsfrag(la, arow + m * 16, kk * 64 + kpart);
#pragma unroll
    for (int n = 0; n < 2; ++n)
#pragma unroll
      for (int kk = 0; kk < 2; ++kk)
        bLo[n * 2 + kk] = ldsfrag(lb, nrow + n * 16, kk * 64 + kpart);
    if (t + 1 < NT) {
      STAGE(A, brow, obuf, 0, 0, t + 1);
      STAGE(A, brow, obuf, 0, 1, t + 1);
    }
    __builtin_amdgcn_s_barrier();
    asm volatile("s_waitcnt lgkmcnt(0)" ::: "memory");
    __builtin_amdgcn_s_setprio(1);
#pragma unroll
    for (int m = 0; m < 4; ++m)
#pragma unroll
      for (int n = 0; n < 2; ++n)
#pragma unroll
        for (int kk = 0; kk < 2; ++kk)
          acc[m][n] = __builtin_amdgcn_mfma_f32_16x16x32_bf16(
              aLo[m * 2 + kk], bLo[n * 2 + kk], acc[m][n], 0, 0, 0);
    __builtin_amdgcn_s_setprio(0);

    // PH2: read aHi; stage B(t+1); MFMA Q(hi,lo)
#pragma unroll
    for (int m = 0; m < 4; ++m)
#pragma unroll
      for (int kk = 0; kk < 2; ++kk)
        aHi[m * 2 + kk] = ldsfrag(la, arow + 64 + m * 16, kk * 64 + kpart);
    if (t + 1 < NT) {
      STAGE(B, bcol, obuf, 32768, 0, t + 1);
      STAGE(B, bcol, obuf, 32768, 1, t + 1);
    }
    __builtin_amdgcn_s_barrier();
    asm volatile("s_waitcnt lgkmcnt(0)" ::: "memory");
    __builtin_amdgcn_s_setprio(1);
#pragma unroll
    for (int m = 0; m < 4; ++m)
#pragma unroll
      for (int n = 0; n < 2; ++n)
#pragma unroll
        for (int kk = 0; kk < 2; ++kk)
          acc[4 + m][n] = __builtin_amdgcn_mfma_f32_16x16x32_bf16(
              aHi[m * 2 + kk], bLo[n * 2 + kk], acc[4 + m][n], 0, 0, 0);
    __builtin_amdgcn_s_setprio(0);

    // PH3: read bHi; MFMA Q(hi,hi)
#pragma unroll
    for (int n = 0; n < 2; ++n)
#pragma unroll
      for (int kk = 0; kk < 2; ++kk)
        bHi[n * 2 + kk] = ldsfrag(lb, nrow + 32 + n * 16, kk * 64 + kpart);
    __builtin_amdgcn_s_barrier();
    asm volatile("s_waitcnt lgkmcnt(0)" ::: "memory");
    __builtin_amdgcn_s_setprio(1);
#pragma unroll
    for (int m = 0; m < 4; ++m)
#pragma unroll
      for (int n = 0; n < 2; ++n)
#pragma unroll
        for (int kk = 0; kk < 2; ++kk)
          acc[4 + m][n + 2] = __builtin_amdgcn_mfma_f32_16x16x32_bf16(
              aHi[m * 2 + kk], bHi[n * 2 + kk], acc[4 + m][n + 2], 0, 0, 0);
    __builtin_amdgcn_s_setprio(0);

    // PH4: vmcnt drain; MFMA Q(lo,hi)
    asm volatile("s_waitcnt vmcnt(0)" ::: "memory");
    __builtin_amdgcn_s_barrier();
    __builtin_amdgcn_s_setprio(1);
#pragma unroll
    for (int m = 0; m < 4; ++m)
#pragma unroll
      for (int n = 0; n < 2; ++n)
#pragma unroll
        for (int kk = 0; kk < 2; ++kk)
          acc[m][n + 2] = __builtin_amdgcn_mfma_f32_16x16x32_bf16(
              aLo[m * 2 + kk], bHi[n * 2 + kk], acc[m][n + 2], 0, 0, 0);
    __builtin_amdgcn_s_setprio(0);
  }
#undef STAGE

  // epilogue
  const int crow0 = brow + wr * 128 + (lane >> 4) * 4;
  const int ccol0 = bcol + wc * 64 + (lane & 15);
#pragma unroll
  for (int m = 0; m < 8; ++m) {
#pragma unroll
    for (int n = 0; n < 4; ++n) {
      const int col = ccol0 + n * 16;
      const float bv = bias[col];
#pragma unroll
      for (int r = 0; r < 4; ++r) {
        const int row = crow0 + m * 16 + r;
        const float v = acc[m][n][r] + bv;
        if (MODE == 1) {
          ((float*)C)[(size_t)row * ldc + col] = v;
        } else if (MODE == 3) {
          int outcol = col;
          if (col >= 768 && col < 1536) {
            const int kc = col - 768;
            outcol = 768 + (kc % 12) * 64 + kc / 12;
          }
          ((unsigned short*)C)[(size_t)row * ldc + outcol] = f2bf(v);
        } else {
          ((unsigned short*)C)[(size_t)row * ldc + col] = f2bf(v);
        }
      }
    }
  }
}

// ---------------- LDS-staged per-token 12x12 attention ----------------
// qkv row: Q[h][d] | KT[g][d] | V[g][d] (each 12x64 bf16, K head-major).
// Block = 256 threads: stage 16 token rows coalesced into LDS (padded +
// swizzled), then 192 threads compute (token, head).
#define T_BLK 16
#define ROWB 4624  // 2304*2 + 16B pad -> +4 bank shift per token

__global__ __launch_bounds__(256)
void attn_kernel(const unsigned short* __restrict__ qkv,
                 unsigned short* __restrict__ ctx) {
  __shared__ __align__(16) char lds[T_BLK * ROWB];  // 73984 B
  const int tid = threadIdx.x;
  const int blk = blockIdx.x;

  // ---- stage: 16 rows = 4608 uint4, fully coalesced ----
  const uint4* src = (const uint4*)(qkv + (size_t)blk * (T_BLK * 2304));
#pragma unroll
  for (int it = 0; it < 18; ++it) {
    const int l = it * 256 + tid;
    const uint4 v = src[l];
    const int tok = l / 288;            // 288 uint4 per row
    const int loff = (l - tok * 288) * 16;
    *(uint4*)(lds + tok * ROWB + swz(loff)) = v;
  }
  __syncthreads();

  if (tid < 192) {
    const int tok = tid / 12;
    const int h = tid - tok * 12;
    const char* rowb = lds + tok * ROWB;

    // Q into registers
    float qd[64];
#pragma unroll
    for (int c = 0; c < 8; ++c) {
      const uint4 qc = *(const uint4*)(rowb + swz(h * 128 + c * 16));
      const unsigned int qw[4] = {qc.x, qc.y, qc.z, qc.w};
#pragma unroll
      for (int w = 0; w < 4; ++w) {
        qd[c * 8 + 2 * w] = bflo(qw[w]);
        qd[c * 8 + 2 * w + 1] = bfhi(qw[w]);
      }
    }

    float s[12];
#pragma unroll
    for (int g = 0; g < 12; ++g) {
      float a = 0.f;
#pragma unroll
      for (int c = 0; c < 8; ++c) {
        const uint4 kc = *(const uint4*)(rowb + swz(1536 + g * 128 + c * 16));
        const unsigned int kw[4] = {kc.x, kc.y, kc.z, kc.w};
#pragma unroll
        for (int w = 0; w < 4; ++w) {
          a += qd[c * 8 + 2 * w] * bflo(kw[w]);
          a += qd[c * 8 + 2 * w + 1] * bfhi(kw[w]);
        }
      }
      s[g] = a;
    }

    float mx = s[0];
#pragma unroll
    for (int g = 1; g < 12; ++g) mx = fmaxf(mx, s[g]);
    float p[12];
    float sum = 0.f;
#pragma unroll
    for (int g = 0; g < 12; ++g) {
      p[g] = __expf((s[g] - mx) * 0.125f);
      sum += p[g];
    }
    const float inv = 1.0f / sum;
#pragma unroll
    for (int g = 0; g < 12; ++g) p[g] *= inv;

    unsigned short* op = ctx + ((size_t)(blk * T_BLK + tok)) * 768 + h * 64;
#pragma unroll
    for (int c = 0; c < 8; ++c) {
      float o[8];
#pragma unroll
      for (int k = 0; k < 8; ++k) o[k] = 0.f;
#pragma unroll
      for (int g = 0; g < 12; ++g) {
        const uint4 vv = *(const uint4*)(rowb + swz(3072 + g * 128 + c * 16));
        const unsigned int vw[4] = {vv.x, vv.y, vv.z, vv.w};
#pragma unroll
        for (int k = 0; k < 4; ++k) {
          o[2 * k] += p[g] * bflo(vw[k]);
          o[2 * k + 1] += p[g] * bfhi(vw[k]);
        }
      }
      uint4 w;
      w.x = (unsigned int)f2bf(o[0]) | ((unsigned int)f2bf(o[1]) << 16);
      w.y = (unsigned int)f2bf(o[2]) | ((unsigned int)f2bf(o[3]) << 16);
      w.z = (unsigned int)f2bf(o[4]) | ((unsigned int)f2bf(o[5]) << 16);
      w.w = (unsigned int)f2bf(o[6]) | ((unsigned int)f2bf(o[7]) << 16);
      *(uint4*)(op + c * 8) = w;
    }
  }
}

extern "C" void kernel_launch(void* const* d_in, const int* in_sizes, int n_in,
                              void* d_out, int out_size, void* d_ws, size_t ws_size,
                              hipStream_t stream) {
  const float* x = (const float*)d_in[0];
  const float* Wq = (const float*)d_in[1];
  const float* bq = (const float*)d_in[2];
  const float* Wk = (const float*)d_in[3];
  const float* bk = (const float*)d_in[4];
  const float* Wv = (const float*)d_in[5];
  const float* bv = (const float*)d_in[6];
  const float* Wo = (const float*)d_in[7];
  const float* bo = (const float*)d_in[8];
  float* out = (float*)d_out;

  char* ws = (char*)d_ws;
  unsigned short* x_bf = (unsigned short*)ws;
  unsigned short* ctx = (unsigned short*)ws;  // alias: x_bf dead before attn
  unsigned short* qkv = (unsigned short*)(ws + 100663296u);
  unsigned short* wqkv = (unsigned short*)(ws + 402653184u);
  unsigned short* wo_bf = (unsigned short*)(ws + 406192128u);
  float* bqkv = (float*)(ws + 407371776u);

  // converts (x + weights + bias concat) in one launch
  cvt_all_kernel<<<51459, 256, 0, stream>>>(x, Wq, Wk, Wv, Wo, bq, bk, bv,
                                            x_bf, wqkv, wo_bf, bqkv);

  // fused QKV GEMM with in-epilogue K head-major remap
  gemm256<3><<<(N_TOK / 256) * (2304 / 256), 512, 0, stream>>>(
      x_bf, wqkv, bqkv, qkv, HIDDEN, 2304 / 256, 2304);

  // LDS-staged per-token attention -> ctx bf16
  attn_kernel<<<N_TOK / T_BLK, 256, 0, stream>>>(qkv, ctx);

  // output projection: [65536 x 768] @ [768 x 768]^T + bo -> out f32
  gemm256<1><<<(N_TOK / 256) * (HIDDEN / 256), 512, 0, stream>>>(
      ctx, wo_bf, bo, out, HIDDEN, HIDDEN / 256, HIDDEN);
}

// Round 11
// 523.403 us; speedup vs baseline: 1.6315x; 1.1835x over previous
//
#include <hip/hip_runtime.h>
#include <hip/hip_bf16.h>
#include <cstdint>
#include <cstddef>

#define N_TOK 65536
#define HIDDEN 768
#define NHEAD 12
#define HEADD 64

typedef __bf16 bf16x8 __attribute__((ext_vector_type(8)));
typedef float f32x4 __attribute__((ext_vector_type(4)));

__device__ __forceinline__ float bflo(unsigned int u) {
  return __builtin_bit_cast(float, (unsigned int)(u << 16));
}
__device__ __forceinline__ float bfhi(unsigned int u) {
  return __builtin_bit_cast(float, (unsigned int)(u & 0xffff0000u));
}
__device__ __forceinline__ unsigned short f2bf(float f) {
  unsigned int x = __builtin_bit_cast(unsigned int, f);
  unsigned int r = x + 0x7fffu + ((x >> 16) & 1u);  // RTNE
  return (unsigned short)(r >> 16);
}

__device__ __forceinline__ void gload_lds16(const void* g, void* l) {
  __builtin_amdgcn_global_load_lds(
      (const __attribute__((address_space(1))) void*)g,
      (__attribute__((address_space(3))) void*)l, 16, 0, 0);
}

// GEMM LDS swizzle: physical = logical ^ ((row&7)<<4). (verified: 0 conflicts)
__device__ __forceinline__ bf16x8 ldsfrag(const char* base, int row, int kb) {
  int L = (row << 7) + kb;
  L ^= (row & 7) << 4;
  return *(const bf16x8*)(base + L);
}

// attn LDS within-row swizzle (16B-unit granular; breaks 128B-stride collisions)
__device__ __forceinline__ int swz(int loff) {
  return loff ^ (((loff >> 7) & 7) << 4);
}

// ------- ALL converts in one launch: x, 4 weights, bias concat -------
__global__ void cvt_all_kernel(const float* __restrict__ x,
                               const float* __restrict__ Wq, const float* __restrict__ Wk,
                               const float* __restrict__ Wv, const float* __restrict__ Wo,
                               const float* __restrict__ bq, const float* __restrict__ bk,
                               const float* __restrict__ bv,
                               unsigned short* __restrict__ x_bf,
                               unsigned short* __restrict__ wqkv,
                               unsigned short* __restrict__ wo_bf,
                               float* __restrict__ bqkv) {
  const int bid = blockIdx.x;
  if (bid < 49152) {
    const int idx = bid * 256 + threadIdx.x;
    float4 v = ((const float4*)x)[idx];
    ushort4 o;
    o.x = f2bf(v.x); o.y = f2bf(v.y); o.z = f2bf(v.z); o.w = f2bf(v.w);
    ((ushort4*)x_bf)[idx] = o;
  } else if (bid < 51456) {
    const int wb = bid - 49152;
    const int mat = wb / 576;
    const int idx = (wb - mat * 576) * 256 + threadIdx.x;
    const float* src = mat == 0 ? Wq : mat == 1 ? Wk : mat == 2 ? Wv : Wo;
    unsigned short* dst = (mat == 3) ? wo_bf : wqkv + mat * (HIDDEN * HIDDEN);
    float4 v = ((const float4*)src)[idx];
    ushort4 o;
    o.x = f2bf(v.x); o.y = f2bf(v.y); o.z = f2bf(v.z); o.w = f2bf(v.w);
    ((ushort4*)dst)[idx] = o;
  } else {
    const int i = (bid - 51456) * 256 + threadIdx.x;
    if (i < 576) {
      const float* src = i < 192 ? bq : i < 384 ? bk : bv;
      const int off = i < 192 ? i : i < 384 ? i - 192 : i - 384;
      ((float4*)bqkv)[i] = ((const float4*)src)[off];
    }
  }
}

// ------------- 256x256 bf16 GEMM, C = A @ B^T + bias (R4/R8 config) -------------
// MODE 0: bf16 out.  MODE 1: f32 out.
template <int MODE>
__global__ __launch_bounds__(512, 2)
void gemm256(const unsigned short* __restrict__ A,
             const unsigned short* __restrict__ B,
             const float* __restrict__ bias,
             void* __restrict__ C, int K, int NBLK, int ldc) {
  __shared__ __align__(16) char lds[131072];
  const int tid = threadIdx.x;
  const int lane = tid & 63;
  const int wave = tid >> 6;
  const int wr = wave >> 2;
  const int wc = wave & 3;

  const int nwg = gridDim.x;
  const int bid = blockIdx.x;
  const int wg = (bid & 7) * (nwg >> 3) + (bid >> 3);
  const int mb = wg / NBLK;
  const int nb = wg - mb * NBLK;
  const int brow = mb << 8;
  const int bcol = nb << 8;

  const int Ld = tid * 16;
  const int Ls = Ld ^ (((tid >> 3) & 7) << 4);
  const int sr = Ls >> 7;
  const int sc = (Ls & 127) >> 1;

  const int NT = K >> 6;

#define STAGE(Mat, panelRow, bufbase, matoff, half, kt)                         \
  do {                                                                          \
    const unsigned short* _s =                                                  \
        (Mat) + (size_t)((panelRow) + (half) * 128 + sr) * K + ((kt) << 6) + sc;\
    char* _d = (char*)lds + (bufbase) + (matoff) + ((half) << 14) + Ld;         \
    gload_lds16(_s, _d);                                                        \
    gload_lds16(_s + ((size_t)K << 6), _d + 8192);                              \
  } while (0)

  f32x4 acc[8][4];
#pragma unroll
  for (int m = 0; m < 8; ++m)
#pragma unroll
    for (int n = 0; n < 4; ++n) acc[m][n] = (f32x4){0.f, 0.f, 0.f, 0.f};

  const int arow = wr * 128 + (lane & 15);
  const int nrow = wc * 64 + (lane & 15);
  const int kpart = (lane >> 4) * 16;

  STAGE(A, brow, 0, 0, 0, 0);
  STAGE(A, brow, 0, 0, 1, 0);
  STAGE(B, bcol, 0, 32768, 0, 0);
  STAGE(B, bcol, 0, 32768, 1, 0);
  asm volatile("s_waitcnt vmcnt(0)" ::: "memory");
  __builtin_amdgcn_s_barrier();

  for (int t = 0; t < NT; ++t) {
    const int cur = t & 1;
    const char* la = lds + cur * 65536;
    const char* lb = la + 32768;
    const int obuf = (cur ^ 1) * 65536;

    bf16x8 aLo[8], aHi[8], bLo[4], bHi[4];

    // PH1
#pragma unroll
    for (int m = 0; m < 4; ++m)
#pragma unroll
      for (int kk = 0; kk < 2; ++kk)
        aLo[m * 2 + kk] = ldsfrag(la, arow + m * 16, kk * 64 + kpart);
#pragma unroll
    for (int n = 0; n < 2; ++n)
#pragma unroll
      for (int kk = 0; kk < 2; ++kk)
        bLo[n * 2 + kk] = ldsfrag(lb, nrow + n * 16, kk * 64 + kpart);
    if (t + 1 < NT) {
      STAGE(A, brow, obuf, 0, 0, t + 1);
      STAGE(A, brow, obuf, 0, 1, t + 1);
    }
    __builtin_amdgcn_s_barrier();
    asm volatile("s_waitcnt lgkmcnt(0)" ::: "memory");
    __builtin_amdgcn_s_setprio(1);
#pragma unroll
    for (int m = 0; m < 4; ++m)
#pragma unroll
      for (int n = 0; n < 2; ++n)
#pragma unroll
        for (int kk = 0; kk < 2; ++kk)
          acc[m][n] = __builtin_amdgcn_mfma_f32_16x16x32_bf16(
              aLo[m * 2 + kk], bLo[n * 2 + kk], acc[m][n], 0, 0, 0);
    __builtin_amdgcn_s_setprio(0);

    // PH2
#pragma unroll
    for (int m = 0; m < 4; ++m)
#pragma unroll
      for (int kk = 0; kk < 2; ++kk)
        aHi[m * 2 + kk] = ldsfrag(la, arow + 64 + m * 16, kk * 64 + kpart);
    if (t + 1 < NT) {
      STAGE(B, bcol, obuf, 32768, 0, t + 1);
      STAGE(B, bcol, obuf, 32768, 1, t + 1);
    }
    __builtin_amdgcn_s_barrier();
    asm volatile("s_waitcnt lgkmcnt(0)" ::: "memory");
    __builtin_amdgcn_s_setprio(1);
#pragma unroll
    for (int m = 0; m < 4; ++m)
#pragma unroll
      for (int n = 0; n < 2; ++n)
#pragma unroll
        for (int kk = 0; kk < 2; ++kk)
          acc[4 + m][n] = __builtin_amdgcn_mfma_f32_16x16x32_bf16(
              aHi[m * 2 + kk], bLo[n * 2 + kk], acc[4 + m][n], 0, 0, 0);
    __builtin_amdgcn_s_setprio(0);

    // PH3
#pragma unroll
    for (int n = 0; n < 2; ++n)
#pragma unroll
      for (int kk = 0; kk < 2; ++kk)
        bHi[n * 2 + kk] = ldsfrag(lb, nrow + 32 + n * 16, kk * 64 + kpart);
    __builtin_amdgcn_s_barrier();
    asm volatile("s_waitcnt lgkmcnt(0)" ::: "memory");
    __builtin_amdgcn_s_setprio(1);
#pragma unroll
    for (int m = 0; m < 4; ++m)
#pragma unroll
      for (int n = 0; n < 2; ++n)
#pragma unroll
        for (int kk = 0; kk < 2; ++kk)
          acc[4 + m][n + 2] = __builtin_amdgcn_mfma_f32_16x16x32_bf16(
              aHi[m * 2 + kk], bHi[n * 2 + kk], acc[4 + m][n + 2], 0, 0, 0);
    __builtin_amdgcn_s_setprio(0);

    // PH4
    asm volatile("s_waitcnt vmcnt(0)" ::: "memory");
    __builtin_amdgcn_s_barrier();
    __builtin_amdgcn_s_setprio(1);
#pragma unroll
    for (int m = 0; m < 4; ++m)
#pragma unroll
      for (int n = 0; n < 2; ++n)
#pragma unroll
        for (int kk = 0; kk < 2; ++kk)
          acc[m][n + 2] = __builtin_amdgcn_mfma_f32_16x16x32_bf16(
              aLo[m * 2 + kk], bHi[n * 2 + kk], acc[m][n + 2], 0, 0, 0);
    __builtin_amdgcn_s_setprio(0);
  }
#undef STAGE

  const int crow0 = brow + wr * 128 + (lane >> 4) * 4;
  const int ccol0 = bcol + wc * 64 + (lane & 15);
#pragma unroll
  for (int m = 0; m < 8; ++m) {
#pragma unroll
    for (int n = 0; n < 4; ++n) {
      const int col = ccol0 + n * 16;
      const float bv = bias[col];
#pragma unroll
      for (int r = 0; r < 4; ++r) {
        const int row = crow0 + m * 16 + r;
        const float v = acc[m][n][r] + bv;
        if (MODE == 1)
          ((float*)C)[(size_t)row * ldc + col] = v;
        else
          ((unsigned short*)C)[(size_t)row * ldc + col] = f2bf(v);
      }
    }
  }
}

// ---------------- LDS-staged per-token 12x12 attention ----------------
// qkv row natural layout: Q[h][d] | K[d][g] | V[g][d].
// Block: 256 threads stage 16 token rows coalesced into swizzled LDS;
// 192 threads compute (token, head). K read d-major via 3 x uint2 per d
// (24B contiguous, broadcast across the 12 heads of a token).
#define T_BLK 16
#define ROWB 4624  // 4608 + 16B pad -> +4 bank shift per token

__global__ __launch_bounds__(256)
void attn_kernel(const unsigned short* __restrict__ qkv,
                 unsigned short* __restrict__ ctx) {
  __shared__ __align__(16) char lds[T_BLK * ROWB];  // 73984 B
  const int tid = threadIdx.x;
  const int blk = blockIdx.x;

  // ---- stage: 16 rows = 4608 uint4, fully coalesced ----
  const uint4* src = (const uint4*)(qkv + (size_t)blk * (T_BLK * 2304));
#pragma unroll
  for (int it = 0; it < 18; ++it) {
    const int l = it * 256 + tid;
    const uint4 v = src[l];
    const int tok = l / 288;
    const int loff = (l - tok * 288) * 16;
    *(uint4*)(lds + tok * ROWB + swz(loff)) = v;
  }
  __syncthreads();

  if (tid < 192) {
    const int tok = tid / 12;
    const int h = tid - tok * 12;
    const char* rowb = lds + tok * ROWB;

    // QK^T: iterate d in chunks of 8; K rows read as 3 x uint2 (d-major)
    float s[12];
#pragma unroll
    for (int g = 0; g < 12; ++g) s[g] = 0.f;
#pragma unroll
    for (int c = 0; c < 8; ++c) {
      const uint4 qc = *(const uint4*)(rowb + swz(h * 128 + c * 16));
      const unsigned int qw[4] = {qc.x, qc.y, qc.z, qc.w};
      float qd[8];
#pragma unroll
      for (int w = 0; w < 4; ++w) {
        qd[2 * w] = bflo(qw[w]);
        qd[2 * w + 1] = bfhi(qw[w]);
      }
#pragma unroll
      for (int j = 0; j < 8; ++j) {
        const int koff = 1536 + (c * 8 + j) * 24;  // K[d][0..11], d=c*8+j
        const uint2 k0 = *(const uint2*)(rowb + swz(koff));
        const uint2 k1 = *(const uint2*)(rowb + swz(koff + 8));
        const uint2 k2 = *(const uint2*)(rowb + swz(koff + 16));
        const float q = qd[j];
        s[0] += q * bflo(k0.x);  s[1] += q * bfhi(k0.x);
        s[2] += q * bflo(k0.y);  s[3] += q * bfhi(k0.y);
        s[4] += q * bflo(k1.x);  s[5] += q * bfhi(k1.x);
        s[6] += q * bflo(k1.y);  s[7] += q * bfhi(k1.y);
        s[8] += q * bflo(k2.x);  s[9] += q * bfhi(k2.x);
        s[10] += q * bflo(k2.y); s[11] += q * bfhi(k2.y);
      }
    }

    float mx = s[0];
#pragma unroll
    for (int g = 1; g < 12; ++g) mx = fmaxf(mx, s[g]);
    float p[12];
    float sum = 0.f;
#pragma unroll
    for (int g = 0; g < 12; ++g) {
      p[g] = __expf((s[g] - mx) * 0.125f);
      sum += p[g];
    }
    const float inv = 1.0f / sum;
#pragma unroll
    for (int g = 0; g < 12; ++g) p[g] *= inv;

    unsigned short* op = ctx + ((size_t)(blk * T_BLK + tok)) * 768 + h * 64;
#pragma unroll
    for (int c = 0; c < 8; ++c) {
      float o[8];
#pragma unroll
      for (int k = 0; k < 8; ++k) o[k] = 0.f;
#pragma unroll
      for (int g = 0; g < 12; ++g) {
        const uint4 vv = *(const uint4*)(rowb + swz(3072 + g * 128 + c * 16));
        const unsigned int vw[4] = {vv.x, vv.y, vv.z, vv.w};
#pragma unroll
        for (int k = 0; k < 4; ++k) {
          o[2 * k] += p[g] * bflo(vw[k]);
          o[2 * k + 1] += p[g] * bfhi(vw[k]);
        }
      }
      uint4 w;
      w.x = (unsigned int)f2bf(o[0]) | ((unsigned int)f2bf(o[1]) << 16);
      w.y = (unsigned int)f2bf(o[2]) | ((unsigned int)f2bf(o[3]) << 16);
      w.z = (unsigned int)f2bf(o[4]) | ((unsigned int)f2bf(o[5]) << 16);
      w.w = (unsigned int)f2bf(o[6]) | ((unsigned int)f2bf(o[7]) << 16);
      *(uint4*)(op + c * 8) = w;
    }
  }
}

extern "C" void kernel_launch(void* const* d_in, const int* in_sizes, int n_in,
                              void* d_out, int out_size, void* d_ws, size_t ws_size,
                              hipStream_t stream) {
  const float* x = (const float*)d_in[0];
  const float* Wq = (const float*)d_in[1];
  const float* bq = (const float*)d_in[2];
  const float* Wk = (const float*)d_in[3];
  const float* bk = (const float*)d_in[4];
  const float* Wv = (const float*)d_in[5];
  const float* bv = (const float*)d_in[6];
  const float* Wo = (const float*)d_in[7];
  const float* bo = (const float*)d_in[8];
  float* out = (float*)d_out;

  char* ws = (char*)d_ws;
  unsigned short* x_bf = (unsigned short*)ws;
  unsigned short* ctx = (unsigned short*)ws;  // alias: x_bf dead before attn
  unsigned short* qkv = (unsigned short*)(ws + 100663296u);
  unsigned short* wqkv = (unsigned short*)(ws + 402653184u);
  unsigned short* wo_bf = (unsigned short*)(ws + 406192128u);
  float* bqkv = (float*)(ws + 407371776u);

  cvt_all_kernel<<<51459, 256, 0, stream>>>(x, Wq, Wk, Wv, Wo, bq, bk, bv,
                                            x_bf, wqkv, wo_bf, bqkv);

  // fused QKV GEMM (plain layout)
  gemm256<0><<<(N_TOK / 256) * (2304 / 256), 512, 0, stream>>>(
      x_bf, wqkv, bqkv, qkv, HIDDEN, 2304 / 256, 2304);

  // LDS-staged per-token attention -> ctx bf16
  attn_kernel<<<N_TOK / T_BLK, 256, 0, stream>>>(qkv, ctx);

  // output projection -> out f32
  gemm256<1><<<(N_TOK / 256) * (HIDDEN / 256), 512, 0, stream>>>(
      ctx, wo_bf, bo, out, HIDDEN, HIDDEN / 256, HIDDEN);
}

// Round 12
// 518.344 us; speedup vs baseline: 1.6474x; 1.0098x over previous
//
#include <hip/hip_runtime.h>
#include <hip/hip_bf16.h>
#include <cstdint>
#include <cstddef>

#define N_TOK 65536
#define HIDDEN 768
#define NHEAD 12
#define HEADD 64

typedef __bf16 bf16x8 __attribute__((ext_vector_type(8)));
typedef float f32x4 __attribute__((ext_vector_type(4)));

__device__ __forceinline__ float bflo(unsigned int u) {
  return __builtin_bit_cast(float, (unsigned int)(u << 16));
}
__device__ __forceinline__ float bfhi(unsigned int u) {
  return __builtin_bit_cast(float, (unsigned int)(u & 0xffff0000u));
}
__device__ __forceinline__ unsigned short f2bf(float f) {
  unsigned int x = __builtin_bit_cast(unsigned int, f);
  unsigned int r = x + 0x7fffu + ((x >> 16) & 1u);  // RTNE
  return (unsigned short)(r >> 16);
}

__device__ __forceinline__ void gload_lds16(const void* g, void* l) {
  __builtin_amdgcn_global_load_lds(
      (const __attribute__((address_space(1))) void*)g,
      (__attribute__((address_space(3))) void*)l, 16, 0, 0);
}

// GEMM LDS swizzle: physical = logical ^ ((row&7)<<4). (verified: 0 conflicts)
__device__ __forceinline__ bf16x8 ldsfrag(const char* base, int row, int kb) {
  int L = (row << 7) + kb;
  L ^= (row & 7) << 4;
  return *(const bf16x8*)(base + L);
}

// attn LDS within-row swizzle
__device__ __forceinline__ int swz(int loff) {
  return loff ^ (((loff >> 7) & 7) << 4);
}

// ------- ALL converts in one launch: x, 4 weights, bias concat -------
__global__ void cvt_all_kernel(const float* __restrict__ x,
                               const float* __restrict__ Wq, const float* __restrict__ Wk,
                               const float* __restrict__ Wv, const float* __restrict__ Wo,
                               const float* __restrict__ bq, const float* __restrict__ bk,
                               const float* __restrict__ bv,
                               unsigned short* __restrict__ x_bf,
                               unsigned short* __restrict__ wqkv,
                               unsigned short* __restrict__ wo_bf,
                               float* __restrict__ bqkv) {
  const int bid = blockIdx.x;
  if (bid < 49152) {
    const int idx = bid * 256 + threadIdx.x;
    float4 v = ((const float4*)x)[idx];
    ushort4 o;
    o.x = f2bf(v.x); o.y = f2bf(v.y); o.z = f2bf(v.z); o.w = f2bf(v.w);
    ((ushort4*)x_bf)[idx] = o;
  } else if (bid < 51456) {
    const int wb = bid - 49152;
    const int mat = wb / 576;
    const int idx = (wb - mat * 576) * 256 + threadIdx.x;
    const float* src = mat == 0 ? Wq : mat == 1 ? Wk : mat == 2 ? Wv : Wo;
    unsigned short* dst = (mat == 3) ? wo_bf : wqkv + mat * (HIDDEN * HIDDEN);
    float4 v = ((const float4*)src)[idx];
    ushort4 o;
    o.x = f2bf(v.x); o.y = f2bf(v.y); o.z = f2bf(v.z); o.w = f2bf(v.w);
    ((ushort4*)dst)[idx] = o;
  } else {
    const int i = (bid - 51456) * 256 + threadIdx.x;
    if (i < 576) {
      const float* src = i < 192 ? bq : i < 384 ? bk : bv;
      const int off = i < 192 ? i : i < 384 ? i - 192 : i - 384;
      ((float4*)bqkv)[i] = ((const float4*)src)[off];
    }
  }
}

// ------------- 256x256 bf16 GEMM, 1024 thr = 16 waves (4M x 4N) -------------
// Per-wave 64x64 output (acc = 64 VGPR). R4 4-phase schedule, double-buffered
// 128KB LDS, XOR swizzle, single barrier per phase. 16 waves/CU target.
template <int MODE>  // 0: bf16 out, 1: f32 out
__global__ __launch_bounds__(1024)
void gemm256(const unsigned short* __restrict__ A,
             const unsigned short* __restrict__ B,
             const float* __restrict__ bias,
             void* __restrict__ C, int K, int NBLK, int ldc) {
  __shared__ __align__(16) char lds[131072];
  const int tid = threadIdx.x;
  const int lane = tid & 63;
  const int wave = tid >> 6;     // 0..15
  const int wr = wave >> 2;      // 0..3
  const int wc = wave & 3;       // 0..3

  const int nwg = gridDim.x;
  const int bid = blockIdx.x;
  const int wg = (bid & 7) * (nwg >> 3) + (bid >> 3);
  const int mb = wg / NBLK;
  const int nb = wg - mb * NBLK;
  const int brow = mb << 8;
  const int bcol = nb << 8;

  // staging: linear LDS dest (tid*16 covers 16KB = one 128-row half-tile)
  const int Ld = tid * 16;
  const int Ls = Ld ^ (((tid >> 3) & 7) << 4);
  const int sr = Ls >> 7;          // 0..127
  const int sc = (Ls & 127) >> 1;

  const int NT = K >> 6;

#define STAGE(Mat, panelRow, bufbase, matoff, half, kt)                         \
  do {                                                                          \
    const unsigned short* _s =                                                  \
        (Mat) + (size_t)((panelRow) + (half) * 128 + sr) * K + ((kt) << 6) + sc;\
    char* _d = (char*)lds + (bufbase) + (matoff) + ((half) << 14) + Ld;         \
    gload_lds16(_s, _d);                                                        \
  } while (0)

  f32x4 acc[4][4];
#pragma unroll
  for (int m = 0; m < 4; ++m)
#pragma unroll
    for (int n = 0; n < 4; ++n) acc[m][n] = (f32x4){0.f, 0.f, 0.f, 0.f};

  const int arow = wr * 64 + (lane & 15);
  const int nrow = wc * 64 + (lane & 15);
  const int kpart = (lane >> 4) * 16;

  // prologue: stage tile 0 fully, drain, barrier
  STAGE(A, brow, 0, 0, 0, 0);
  STAGE(A, brow, 0, 0, 1, 0);
  STAGE(B, bcol, 0, 32768, 0, 0);
  STAGE(B, bcol, 0, 32768, 1, 0);
  asm volatile("s_waitcnt vmcnt(0)" ::: "memory");
  __builtin_amdgcn_s_barrier();

  for (int t = 0; t < NT; ++t) {
    const int cur = t & 1;
    const char* la = lds + cur * 65536;
    const char* lb = la + 32768;
    const int obuf = (cur ^ 1) * 65536;
    const bool pf = (t + 1 < NT);

    bf16x8 aF[4], bLo[2], bHi[2];

    // ---- PH1: read A-kk0(4)+B-kk0-lo(2); stage A(t+1) h0; MFMA kk0 x nlo ----
#pragma unroll
    for (int m = 0; m < 4; ++m) aF[m] = ldsfrag(la, arow + m * 16, kpart);
#pragma unroll
    for (int n = 0; n < 2; ++n) bLo[n] = ldsfrag(lb, nrow + n * 16, kpart);
    if (pf) STAGE(A, brow, obuf, 0, 0, t + 1);
    __builtin_amdgcn_s_barrier();
    asm volatile("s_waitcnt lgkmcnt(0)" ::: "memory");
    __builtin_amdgcn_sched_barrier(0);
    __builtin_amdgcn_s_setprio(1);
#pragma unroll
    for (int m = 0; m < 4; ++m)
#pragma unroll
      for (int n = 0; n < 2; ++n)
        acc[m][n] = __builtin_amdgcn_mfma_f32_16x16x32_bf16(aF[m], bLo[n],
                                                            acc[m][n], 0, 0, 0);
    __builtin_amdgcn_s_setprio(0);

    // ---- PH2: read B-kk0-hi(2); stage A(t+1) h1; MFMA kk0 x nhi ----
#pragma unroll
    for (int n = 0; n < 2; ++n) bHi[n] = ldsfrag(lb, nrow + 32 + n * 16, kpart);
    if (pf) STAGE(A, brow, obuf, 0, 1, t + 1);
    __builtin_amdgcn_s_barrier();
    asm volatile("s_waitcnt lgkmcnt(0)" ::: "memory");
    __builtin_amdgcn_sched_barrier(0);
    __builtin_amdgcn_s_setprio(1);
#pragma unroll
    for (int m = 0; m < 4; ++m)
#pragma unroll
      for (int n = 0; n < 2; ++n)
        acc[m][n + 2] = __builtin_amdgcn_mfma_f32_16x16x32_bf16(
            aF[m], bHi[n], acc[m][n + 2], 0, 0, 0);
    __builtin_amdgcn_s_setprio(0);

    // ---- PH3: read A-kk1(4)+B-kk1-lo(2); stage B(t+1) h0; MFMA kk1 x nlo ----
#pragma unroll
    for (int m = 0; m < 4; ++m) aF[m] = ldsfrag(la, arow + m * 16, 64 + kpart);
#pragma unroll
    for (int n = 0; n < 2; ++n) bLo[n] = ldsfrag(lb, nrow + n * 16, 64 + kpart);
    if (pf) STAGE(B, bcol, obuf, 32768, 0, t + 1);
    __builtin_amdgcn_s_barrier();
    asm volatile("s_waitcnt lgkmcnt(0)" ::: "memory");
    __builtin_amdgcn_sched_barrier(0);
    __builtin_amdgcn_s_setprio(1);
#pragma unroll
    for (int m = 0; m < 4; ++m)
#pragma unroll
      for (int n = 0; n < 2; ++n)
        acc[m][n] = __builtin_amdgcn_mfma_f32_16x16x32_bf16(aF[m], bLo[n],
                                                            acc[m][n], 0, 0, 0);
    __builtin_amdgcn_s_setprio(0);

    // ---- PH4: read B-kk1-hi(2); stage B(t+1) h1; vmcnt(0); MFMA kk1 x nhi ----
#pragma unroll
    for (int n = 0; n < 2; ++n)
      bHi[n] = ldsfrag(lb, nrow + 32 + n * 16, 64 + kpart);
    if (pf) STAGE(B, bcol, obuf, 32768, 1, t + 1);
    asm volatile("s_waitcnt vmcnt(0)" ::: "memory");
    __builtin_amdgcn_s_barrier();
    asm volatile("s_waitcnt lgkmcnt(0)" ::: "memory");
    __builtin_amdgcn_sched_barrier(0);
    __builtin_amdgcn_s_setprio(1);
#pragma unroll
    for (int m = 0; m < 4; ++m)
#pragma unroll
      for (int n = 0; n < 2; ++n)
        acc[m][n + 2] = __builtin_amdgcn_mfma_f32_16x16x32_bf16(
            aF[m], bHi[n], acc[m][n + 2], 0, 0, 0);
    __builtin_amdgcn_s_setprio(0);
  }
#undef STAGE

  // epilogue: per-wave 64x64
  const int crow0 = brow + wr * 64 + (lane >> 4) * 4;
  const int ccol0 = bcol + wc * 64 + (lane & 15);
#pragma unroll
  for (int m = 0; m < 4; ++m) {
#pragma unroll
    for (int n = 0; n < 4; ++n) {
      const int col = ccol0 + n * 16;
      const float bv = bias[col];
#pragma unroll
      for (int r = 0; r < 4; ++r) {
        const int row = crow0 + m * 16 + r;
        const float v = acc[m][n][r] + bv;
        if (MODE == 1)
          ((float*)C)[(size_t)row * ldc + col] = v;
        else
          ((unsigned short*)C)[(size_t)row * ldc + col] = f2bf(v);
      }
    }
  }
}

// ---------------- LDS-staged per-token 12x12 attention (R11, working) ---------
#define T_BLK 16
#define ROWB 4624

__global__ __launch_bounds__(256)
void attn_kernel(const unsigned short* __restrict__ qkv,
                 unsigned short* __restrict__ ctx) {
  __shared__ __align__(16) char lds[T_BLK * ROWB];
  const int tid = threadIdx.x;
  const int blk = blockIdx.x;

  const uint4* src = (const uint4*)(qkv + (size_t)blk * (T_BLK * 2304));
#pragma unroll
  for (int it = 0; it < 18; ++it) {
    const int l = it * 256 + tid;
    const uint4 v = src[l];
    const int tok = l / 288;
    const int loff = (l - tok * 288) * 16;
    *(uint4*)(lds + tok * ROWB + swz(loff)) = v;
  }
  __syncthreads();

  if (tid < 192) {
    const int tok = tid / 12;
    const int h = tid - tok * 12;
    const char* rowb = lds + tok * ROWB;

    float s[12];
#pragma unroll
    for (int g = 0; g < 12; ++g) s[g] = 0.f;
#pragma unroll
    for (int c = 0; c < 8; ++c) {
      const uint4 qc = *(const uint4*)(rowb + swz(h * 128 + c * 16));
      const unsigned int qw[4] = {qc.x, qc.y, qc.z, qc.w};
      float qd[8];
#pragma unroll
      for (int w = 0; w < 4; ++w) {
        qd[2 * w] = bflo(qw[w]);
        qd[2 * w + 1] = bfhi(qw[w]);
      }
#pragma unroll
      for (int j = 0; j < 8; ++j) {
        const int koff = 1536 + (c * 8 + j) * 24;
        const uint2 k0 = *(const uint2*)(rowb + swz(koff));
        const uint2 k1 = *(const uint2*)(rowb + swz(koff + 8));
        const uint2 k2 = *(const uint2*)(rowb + swz(koff + 16));
        const float q = qd[j];
        s[0] += q * bflo(k0.x);  s[1] += q * bfhi(k0.x);
        s[2] += q * bflo(k0.y);  s[3] += q * bfhi(k0.y);
        s[4] += q * bflo(k1.x);  s[5] += q * bfhi(k1.x);
        s[6] += q * bflo(k1.y);  s[7] += q * bfhi(k1.y);
        s[8] += q * bflo(k2.x);  s[9] += q * bfhi(k2.x);
        s[10] += q * bflo(k2.y); s[11] += q * bfhi(k2.y);
      }
    }

    float mx = s[0];
#pragma unroll
    for (int g = 1; g < 12; ++g) mx = fmaxf(mx, s[g]);
    float p[12];
    float sum = 0.f;
#pragma unroll
    for (int g = 0; g < 12; ++g) {
      p[g] = __expf((s[g] - mx) * 0.125f);
      sum += p[g];
    }
    const float inv = 1.0f / sum;
#pragma unroll
    for (int g = 0; g < 12; ++g) p[g] *= inv;

    unsigned short* op = ctx + ((size_t)(blk * T_BLK + tok)) * 768 + h * 64;
#pragma unroll
    for (int c = 0; c < 8; ++c) {
      float o[8];
#pragma unroll
      for (int k = 0; k < 8; ++k) o[k] = 0.f;
#pragma unroll
      for (int g = 0; g < 12; ++g) {
        const uint4 vv = *(const uint4*)(rowb + swz(3072 + g * 128 + c * 16));
        const unsigned int vw[4] = {vv.x, vv.y, vv.z, vv.w};
#pragma unroll
        for (int k = 0; k < 4; ++k) {
          o[2 * k] += p[g] * bflo(vw[k]);
          o[2 * k + 1] += p[g] * bfhi(vw[k]);
        }
      }
      uint4 w;
      w.x = (unsigned int)f2bf(o[0]) | ((unsigned int)f2bf(o[1]) << 16);
      w.y = (unsigned int)f2bf(o[2]) | ((unsigned int)f2bf(o[3]) << 16);
      w.z = (unsigned int)f2bf(o[4]) | ((unsigned int)f2bf(o[5]) << 16);
      w.w = (unsigned int)f2bf(o[6]) | ((unsigned int)f2bf(o[7]) << 16);
      *(uint4*)(op + c * 8) = w;
    }
  }
}

extern "C" void kernel_launch(void* const* d_in, const int* in_sizes, int n_in,
                              void* d_out, int out_size, void* d_ws, size_t ws_size,
                              hipStream_t stream) {
  const float* x = (const float*)d_in[0];
  const float* Wq = (const float*)d_in[1];
  const float* bq = (const float*)d_in[2];
  const float* Wk = (const float*)d_in[3];
  const float* bk = (const float*)d_in[4];
  const float* Wv = (const float*)d_in[5];
  const float* bv = (const float*)d_in[6];
  const float* Wo = (const float*)d_in[7];
  const float* bo = (const float*)d_in[8];
  float* out = (float*)d_out;

  char* ws = (char*)d_ws;
  unsigned short* x_bf = (unsigned short*)ws;
  unsigned short* ctx = (unsigned short*)ws;  // alias: x_bf dead before attn
  unsigned short* qkv = (unsigned short*)(ws + 100663296u);
  unsigned short* wqkv = (unsigned short*)(ws + 402653184u);
  unsigned short* wo_bf = (unsigned short*)(ws + 406192128u);
  float* bqkv = (float*)(ws + 407371776u);

  cvt_all_kernel<<<51459, 256, 0, stream>>>(x, Wq, Wk, Wv, Wo, bq, bk, bv,
                                            x_bf, wqkv, wo_bf, bqkv);

  gemm256<0><<<(N_TOK / 256) * (2304 / 256), 1024, 0, stream>>>(
      x_bf, wqkv, bqkv, qkv, HIDDEN, 2304 / 256, 2304);

  attn_kernel<<<N_TOK / T_BLK, 256, 0, stream>>>(qkv, ctx);

  gemm256<1><<<(N_TOK / 256) * (HIDDEN / 256), 1024, 0, stream>>>(
      ctx, wo_bf, bo, out, HIDDEN, HIDDEN / 256, HIDDEN);
}